// Round 2
// baseline (516.759 us; speedup 1.0000x reference)
//
#include <hip/hip_runtime.h>

typedef unsigned short u16;
typedef __attribute__((ext_vector_type(8))) short short8;
typedef __attribute__((ext_vector_type(4))) float f32x4;
typedef __attribute__((ext_vector_type(4))) u16 u16x4;

#define NPT 128
#define DIM 512
#define KT 48
#define KC 32
#define CH 64            // rows per chunk
#define NCHUNK 2

__device__ __forceinline__ u16 f2bf(float f) {
    unsigned u = __builtin_bit_cast(unsigned, f);
    return (u16)((u + 0x7FFFu + ((u >> 16) & 1u)) >> 16);
}

// Fold BN into clusters: cTs[k][d] = bf16(clusters[d][k] * s_k), t[k] = b_k - rm_k*s_k
__global__ void prep_kernel(const float* __restrict__ clusters,
                            const float* __restrict__ bn_w,
                            const float* __restrict__ bn_b,
                            const float* __restrict__ bn_rm,
                            const float* __restrict__ bn_rv,
                            u16* __restrict__ cTs,
                            float* __restrict__ tvec) {
    const int k = blockIdx.x;
    const float s = bn_w[k] * rsqrtf(bn_rv[k] + 1e-5f);
    if (threadIdx.x == 0) tvec[k] = bn_b[k] - bn_rm[k] * s;
    for (int d = threadIdx.x; d < DIM; d += blockDim.x)
        cTs[k * DIM + d] = f2bf(clusters[d * KT + k] * s);
}

__global__ __launch_bounds__(256, 2)
void vlad_kernel(const float* __restrict__ x,
                 const float* __restrict__ c2,     // [512][32] fp32
                 const u16* __restrict__ cTs,      // [48][512] bf16
                 const float* __restrict__ tvec,   // [48]
                 float* __restrict__ out) {
    __shared__ __align__(16) u16 xs[CH * DIM];     // 64 KB, swizzled row-major
    __shared__ __align__(16) u16 aT[KC][72];       // assignment^T for one chunk
    __shared__ float t_s[KT];
    __shared__ float asum_part[4][KC];
    __shared__ float asum_s[KC];
    __shared__ float colsq_part[4][KC];
    __shared__ float scalek[KC];

    const int b    = blockIdx.x;
    const int tid  = threadIdx.x;
    const int wave = tid >> 6;
    const int lane = tid & 63;
    const int lr   = lane & 15;
    const int lg   = lane >> 4;

    if (tid < KT) t_s[tid] = tvec[tid];

    // persistent accumulators: wave owns d in [wave*128, wave*128+128)
    f32x4 vacc[8][2];
    #pragma unroll
    for (int i = 0; i < 8; ++i) {
        vacc[i][0] = (f32x4){0.f,0.f,0.f,0.f};
        vacc[i][1] = (f32x4){0.f,0.f,0.f,0.f};
    }

    for (int c = 0; c < NCHUNK; ++c) {
        __syncthreads();   // xs/aT free from previous chunk's readers

        // ---- stage chunk rows -> bf16 LDS (swizzle: byte ^= (n&7)<<4) ----
        {
            const f32x4* gx = (const f32x4*)(x + (size_t)b * (NPT * DIM) + c * (CH * DIM));
            #pragma unroll 8
            for (int it = 0; it < 32; ++it) {
                int ci = tid + it * 256;         // chunk of 4 floats
                f32x4 v = __builtin_nontemporal_load(&gx[ci]);
                int n  = ci >> 7;                // local row 0..63
                int d0 = (ci & 127) << 2;        // col
                u16x4 w;
                w[0] = f2bf(v[0]); w[1] = f2bf(v[1]); w[2] = f2bf(v[2]); w[3] = f2bf(v[3]);
                int byteoff = n * 1024 + ((2 * d0) ^ ((n & 7) << 4));
                *(u16x4*)((char*)xs + byteoff) = w;
            }
        }
        __syncthreads();

        // ---- phase 1: logits[64][48] for this chunk; wave w rows w*16..+15 ----
        f32x4 acc0 = {0.f,0.f,0.f,0.f}, acc1 = {0.f,0.f,0.f,0.f}, acc2 = {0.f,0.f,0.f,0.f};
        {
            const int nrow = wave * 16 + lr;
            const int rowbase = nrow * 1024;
            const int sw = (nrow & 7) << 4;
            #pragma unroll 4
            for (int step = 0; step < 16; ++step) {
                const int d0 = step * 32 + lg * 8;
                short8 af = *(const short8*)((const char*)xs + (rowbase + ((2 * d0) ^ sw)));
                short8 b0 = *(const short8*)(cTs + (0 * 16 + lr) * DIM + d0);
                short8 b1 = *(const short8*)(cTs + (1 * 16 + lr) * DIM + d0);
                short8 b2 = *(const short8*)(cTs + (2 * 16 + lr) * DIM + d0);
                acc0 = __builtin_amdgcn_mfma_f32_16x16x32_bf16(af, b0, acc0, 0, 0, 0);
                acc1 = __builtin_amdgcn_mfma_f32_16x16x32_bf16(af, b1, acc1, 0, 0, 0);
                acc2 = __builtin_amdgcn_mfma_f32_16x16x32_bf16(af, b2, acc2, 0, 0, 0);
            }
        }
        // ---- softmax over 48, keep 32; write aT bf16; per-wave asum partials ----
        {
            const float t0 = t_s[lr], t1 = t_s[16 + lr], t2 = t_s[32 + lr];
            float a0[4], a1[4];
            #pragma unroll
            for (int r = 0; r < 4; ++r) {
                float l0 = acc0[r] + t0, l1 = acc1[r] + t1, l2 = acc2[r] + t2;
                float m = fmaxf(fmaxf(l0, l1), l2);
                #pragma unroll
                for (int o = 1; o < 16; o <<= 1) m = fmaxf(m, __shfl_xor(m, o));
                float e0 = __expf(l0 - m), e1 = __expf(l1 - m), e2 = __expf(l2 - m);
                float s = e0 + e1 + e2;
                #pragma unroll
                for (int o = 1; o < 16; o <<= 1) s += __shfl_xor(s, o);
                float inv = 1.0f / s;
                a0[r] = e0 * inv; a1[r] = e1 * inv;
            }
            float p0 = 0.f, p1 = 0.f;
            #pragma unroll
            for (int r = 0; r < 4; ++r) {
                int n = wave * 16 + lg * 4 + r;   // local row
                aT[lr][n]      = f2bf(a0[r]);
                aT[16 + lr][n] = f2bf(a1[r]);
                p0 += a0[r]; p1 += a1[r];
            }
            p0 += __shfl_xor(p0, 16); p0 += __shfl_xor(p0, 32);
            p1 += __shfl_xor(p1, 16); p1 += __shfl_xor(p1, 32);
            if (lane < 16) {
                if (c == 0) {
                    asum_part[wave][lane]      = p0;
                    asum_part[wave][16 + lane] = p1;
                } else {
                    asum_part[wave][lane]      += p0;
                    asum_part[wave][16 + lane] += p1;
                }
            }
        }
        __syncthreads();
        if (c == NCHUNK - 1 && tid < KC) {
            float s = 0.f;
            #pragma unroll
            for (int w2 = 0; w2 < 4; ++w2) s += asum_part[w2][tid];
            asum_s[tid] = s;
        }

        // ---- phase 2: vacc += x_chunk^T @ a_chunk ; wave owns d-tiles ----
        #pragma unroll
        for (int ns = 0; ns < 2; ++ns) {
            short8 b0 = *(const short8*)(&aT[lr][ns * 32 + lg * 8]);
            short8 b1 = *(const short8*)(&aT[16 + lr][ns * 32 + lg * 8]);
            #pragma unroll
            for (int dti = 0; dti < 8; ++dti) {
                const int d = wave * 128 + dti * 16 + lr;
                const int base = (ns * 32 + lg * 8) * 1024 + 2 * d;
                short8 af;
                #pragma unroll
                for (int j = 0; j < 8; ++j)
                    af[j] = *(const short*)((const char*)xs + ((base + j * 1024) ^ (j << 4)));
                vacc[dti][0] = __builtin_amdgcn_mfma_f32_16x16x32_bf16(af, b0, vacc[dti][0], 0, 0, 0);
                vacc[dti][1] = __builtin_amdgcn_mfma_f32_16x16x32_bf16(af, b1, vacc[dti][1], 0, 0, 0);
            }
        }
    }
    __syncthreads();   // asum_s visible; all phase-2 done

    // ---- epilogue: subtract asum*c2, column sumsq partials ----
    float cs0 = 0.f, cs1 = 0.f;
    {
        const float as0 = asum_s[lr], as1 = asum_s[16 + lr];
        #pragma unroll
        for (int dti = 0; dti < 8; ++dti) {
            #pragma unroll
            for (int r = 0; r < 4; ++r) {
                int d = wave * 128 + dti * 16 + lg * 4 + r;
                float v0 = vacc[dti][0][r] - as0 * c2[d * KC + lr];
                float v1 = vacc[dti][1][r] - as1 * c2[d * KC + 16 + lr];
                vacc[dti][0][r] = v0; vacc[dti][1][r] = v1;
                cs0 += v0 * v0; cs1 += v1 * v1;
            }
        }
    }
    cs0 += __shfl_xor(cs0, 16); cs0 += __shfl_xor(cs0, 32);
    cs1 += __shfl_xor(cs1, 16); cs1 += __shfl_xor(cs1, 32);
    if (lane < 16) { colsq_part[wave][lane] = cs0; colsq_part[wave][16 + lane] = cs1; }
    __syncthreads();
    if (tid < KC) {
        float sq = 0.f;
        #pragma unroll
        for (int w2 = 0; w2 < 4; ++w2) sq += colsq_part[w2][tid];
        float cn = sqrtf(sq);
        float s1 = 1.0f / fmaxf(cn, 1e-12f);
        float c1 = cn * s1;
        float tot = c1 * c1;
        #pragma unroll
        for (int o = 1; o < 32; o <<= 1) tot += __shfl_xor(tot, o);
        scalek[tid] = s1 * (1.0f / fmaxf(sqrtf(tot), 1e-12f));
    }
    __syncthreads();
    {
        float* ob = out + (size_t)b * (DIM * KC);
        const float sk0 = scalek[lr], sk1 = scalek[16 + lr];
        #pragma unroll
        for (int dti = 0; dti < 8; ++dti) {
            #pragma unroll
            for (int r = 0; r < 4; ++r) {
                int d = wave * 128 + dti * 16 + lg * 4 + r;
                ob[d * KC + lr]      = vacc[dti][0][r] * sk0;
                ob[d * KC + 16 + lr] = vacc[dti][1][r] * sk1;
            }
        }
    }
}

extern "C" void kernel_launch(void* const* d_in, const int* in_sizes, int n_in,
                              void* d_out, int out_size, void* d_ws, size_t ws_size,
                              hipStream_t stream) {
    const float* x        = (const float*)d_in[0];
    const float* clusters = (const float*)d_in[1];
    const float* bn_w     = (const float*)d_in[2];
    const float* bn_b     = (const float*)d_in[3];
    const float* bn_rm    = (const float*)d_in[4];
    const float* bn_rv    = (const float*)d_in[5];
    const float* c2       = (const float*)d_in[6];
    float* out = (float*)d_out;

    u16*   cTs  = (u16*)d_ws;
    float* tvec = (float*)((char*)d_ws + KT * DIM * sizeof(u16));

    const int B = in_sizes[0] / (NPT * DIM);

    prep_kernel<<<KT, 256, 0, stream>>>(clusters, bn_w, bn_b, bn_rm, bn_rv, cTs, tvec);
    vlad_kernel<<<B, 256, 0, stream>>>(x, c2, cTs, tvec, out);
}

// Round 4
// 438.206 us; speedup vs baseline: 1.1793x; 1.1793x over previous
//
#include <hip/hip_runtime.h>

typedef unsigned short u16;
typedef unsigned int u32;
typedef __attribute__((ext_vector_type(8))) short short8;
typedef __attribute__((ext_vector_type(4))) float f32x4;
typedef __attribute__((ext_vector_type(2))) u32 u32x2;

#define NPT 128
#define DIM 512
#define KT 48
#define KC 32

__device__ __forceinline__ u16 f2bf(float f) {
    unsigned u = __builtin_bit_cast(unsigned, f);
    return (u16)((u + 0x7FFFu + ((u >> 16) & 1u)) >> 16);
}

__device__ __forceinline__ u32 cvtpk(float lo, float hi) {
    u32 r;
    asm("v_cvt_pk_bf16_f32 %0, %1, %2" : "=v"(r) : "v"(lo), "v"(hi));
    return r;
}

// bank swizzle: 16B-granular XOR inside a 1KB row; distinct for rows n..n+7
// (phase-1 groups) AND for rows n, n+8, n+16, n+24 (phase-2 gather groups)
__device__ __forceinline__ int swz(int n) {
    return ((n & 7) ^ ((n >> 3) & 7)) << 4;
}

// Fold BN into clusters: cTs[k][d] = bf16(clusters[d][k] * s_k), t[k] = b_k - rm_k*s_k
__global__ void prep_kernel(const float* __restrict__ clusters,
                            const float* __restrict__ bn_w,
                            const float* __restrict__ bn_b,
                            const float* __restrict__ bn_rm,
                            const float* __restrict__ bn_rv,
                            u16* __restrict__ cTs,
                            float* __restrict__ tvec) {
    const int k = blockIdx.x;
    const float s = bn_w[k] * rsqrtf(bn_rv[k] + 1e-5f);
    if (threadIdx.x == 0) tvec[k] = bn_b[k] - bn_rm[k] * s;
    for (int d = threadIdx.x; d < DIM; d += blockDim.x)
        cTs[k * DIM + d] = f2bf(clusters[d * KT + k] * s);
}

__global__ __launch_bounds__(512)
void vlad_kernel(const float* __restrict__ x,
                 const float* __restrict__ c2,     // [512][32] fp32
                 const u16* __restrict__ cTs,      // [48][512] bf16
                 const float* __restrict__ tvec,   // [48]
                 float* __restrict__ out) {
    __shared__ __align__(16) u16 xs[NPT * DIM];    // 128 KB, swizzled row-major
    __shared__ __align__(16) u16 aT[KC][136];      // assignment^T (n up to 128; +8 pad)
    __shared__ float asum_part[8][KC];
    __shared__ float asum_s[KC];
    __shared__ float colsq_part[8][KC];
    __shared__ float scalek[KC];

    const int b    = blockIdx.x;
    const int tid  = threadIdx.x;
    const int wave = tid >> 6;
    const int lane = tid & 63;
    const int lr   = lane & 15;
    const int lg   = lane >> 4;

    // ---- wave-self staging: wave w stages rows [16w, 16w+16) -> no barrier
    // before phase 1 (each wave's phase-1 A-frags read only its own rows) ----
    {
        const float* gxw = x + (size_t)b * (NPT * DIM) + (wave * 16) * DIM;
        #pragma unroll
        for (int bt = 0; bt < 4; ++bt) {
            f32x4 tmp[8];
            #pragma unroll
            for (int i = 0; i < 8; ++i) {
                int it = bt * 8 + i;
                tmp[i] = *(const f32x4*)(gxw + (it >> 1) * DIM + (it & 1) * 256 + lane * 4);
            }
            #pragma unroll
            for (int i = 0; i < 8; ++i) {
                int it = bt * 8 + i;
                int r = wave * 16 + (it >> 1);
                u32x2 w2;
                w2[0] = cvtpk(tmp[i][0], tmp[i][1]);
                w2[1] = cvtpk(tmp[i][2], tmp[i][3]);
                int off = ((it & 1) * 512 + lane * 8) ^ swz(r);
                *(u32x2*)((char*)xs + r * 1024 + off) = w2;
            }
        }
    }

    // ---- phase 1: logits[128][48]; wave w owns rows w*16..w*16+15 ----
    f32x4 acc0 = {0.f,0.f,0.f,0.f}, acc1 = {0.f,0.f,0.f,0.f}, acc2 = {0.f,0.f,0.f,0.f};
    {
        const int nrow = wave * 16 + lr;
        const int rowbase = nrow * 1024;
        const int sw = swz(nrow);
        #pragma unroll 2
        for (int step = 0; step < 16; ++step) {
            const int d0 = step * 32 + lg * 8;
            short8 af = *(const short8*)((const char*)xs + (rowbase + ((2 * d0) ^ sw)));
            short8 b0 = *(const short8*)(cTs + (0 * 16 + lr) * DIM + d0);
            short8 b1 = *(const short8*)(cTs + (1 * 16 + lr) * DIM + d0);
            short8 b2 = *(const short8*)(cTs + (2 * 16 + lr) * DIM + d0);
            acc0 = __builtin_amdgcn_mfma_f32_16x16x32_bf16(af, b0, acc0, 0, 0, 0);
            acc1 = __builtin_amdgcn_mfma_f32_16x16x32_bf16(af, b1, acc1, 0, 0, 0);
            acc2 = __builtin_amdgcn_mfma_f32_16x16x32_bf16(af, b2, acc2, 0, 0, 0);
        }
    }
    // ---- softmax over 48, keep 32; write aT bf16; per-wave asum partials ----
    {
        const float t0 = tvec[lr], t1 = tvec[16 + lr], t2 = tvec[32 + lr];
        float a0[4], a1[4];
        #pragma unroll
        for (int r = 0; r < 4; ++r) {
            float l0 = acc0[r] + t0, l1 = acc1[r] + t1, l2 = acc2[r] + t2;
            float m = fmaxf(fmaxf(l0, l1), l2);
            #pragma unroll
            for (int o = 1; o < 16; o <<= 1) m = fmaxf(m, __shfl_xor(m, o));
            float e0 = __expf(l0 - m), e1 = __expf(l1 - m), e2 = __expf(l2 - m);
            float s = e0 + e1 + e2;
            #pragma unroll
            for (int o = 1; o < 16; o <<= 1) s += __shfl_xor(s, o);
            float inv = 1.0f / s;
            a0[r] = e0 * inv; a1[r] = e1 * inv;
        }
        float p0 = 0.f, p1 = 0.f;
        #pragma unroll
        for (int r = 0; r < 4; ++r) {
            int n = wave * 16 + lg * 4 + r;
            aT[lr][n]      = f2bf(a0[r]);
            aT[16 + lr][n] = f2bf(a1[r]);
            p0 += a0[r]; p1 += a1[r];
        }
        p0 += __shfl_xor(p0, 16); p0 += __shfl_xor(p0, 32);
        p1 += __shfl_xor(p1, 16); p1 += __shfl_xor(p1, 32);
        if (lane < 16) { asum_part[wave][lane] = p0; asum_part[wave][16 + lane] = p1; }
    }
    __syncthreads();   // barrier 1: xs (all rows), aT, asum_part complete
    if (tid < KC) {
        float s = 0.f;
        #pragma unroll
        for (int w2 = 0; w2 < 8; ++w2) s += asum_part[w2][tid];
        asum_s[tid] = s;
    }

    // ---- phase 2: vlad[512][32] = x^T @ a ; wave w owns d-tiles w*4..w*4+3 ----
    f32x4 vacc[4][2];
    #pragma unroll
    for (int i = 0; i < 4; ++i) {
        vacc[i][0] = (f32x4){0.f,0.f,0.f,0.f};
        vacc[i][1] = (f32x4){0.f,0.f,0.f,0.f};
    }
    #pragma unroll
    for (int ns = 0; ns < 4; ++ns) {
        short8 b0 = *(const short8*)(&aT[lr][ns * 32 + lg * 8]);
        short8 b1 = *(const short8*)(&aT[16 + lr][ns * 32 + lg * 8]);
        const int n0 = ns * 32 + lg * 8;
        const int q  = (ns * 4 + lg) & 7;
        const char* pbase = (const char*)xs + n0 * 1024;
        #pragma unroll
        for (int dti = 0; dti < 4; ++dti) {
            const int d = (wave * 4 + dti) * 16 + lr;
            const int twod = 2 * d;
            short8 af;
            #pragma unroll
            for (int j = 0; j < 8; ++j)
                af[j] = *(const short*)(pbase + j * 1024 + (twod ^ ((j ^ q) << 4)));
            vacc[dti][0] = __builtin_amdgcn_mfma_f32_16x16x32_bf16(af, b0, vacc[dti][0], 0, 0, 0);
            vacc[dti][1] = __builtin_amdgcn_mfma_f32_16x16x32_bf16(af, b1, vacc[dti][1], 0, 0, 0);
        }
    }
    __syncthreads();   // barrier 2: asum_s visible; aT/xs reads done

    // ---- epilogue: subtract asum*c2, column sumsq partials ----
    float vv[4][2][4];
    float cs0 = 0.f, cs1 = 0.f;
    const float as0 = asum_s[lr], as1 = asum_s[16 + lr];
    #pragma unroll
    for (int dti = 0; dti < 4; ++dti) {
        #pragma unroll
        for (int r = 0; r < 4; ++r) {
            int d = (wave * 4 + dti) * 16 + lg * 4 + r;
            float v0 = vacc[dti][0][r] - as0 * c2[d * KC + lr];
            float v1 = vacc[dti][1][r] - as1 * c2[d * KC + 16 + lr];
            vv[dti][0][r] = v0; vv[dti][1][r] = v1;
            cs0 += v0 * v0; cs1 += v1 * v1;
        }
    }
    cs0 += __shfl_xor(cs0, 16); cs0 += __shfl_xor(cs0, 32);
    cs1 += __shfl_xor(cs1, 16); cs1 += __shfl_xor(cs1, 32);
    if (lane < 16) { colsq_part[wave][lane] = cs0; colsq_part[wave][16 + lane] = cs1; }
    __syncthreads();
    if (tid < KC) {
        float sq = 0.f;
        #pragma unroll
        for (int w2 = 0; w2 < 8; ++w2) sq += colsq_part[w2][tid];
        float cn = sqrtf(sq);
        float s1 = 1.0f / fmaxf(cn, 1e-12f);
        float c1 = cn * s1;
        float tot = c1 * c1;
        #pragma unroll
        for (int o = 1; o < 32; o <<= 1) tot += __shfl_xor(tot, o);
        scalek[tid] = s1 * (1.0f / fmaxf(sqrtf(tot), 1e-12f));
    }
    __syncthreads();
    {
        float* ob = out + (size_t)b * (DIM * KC);
        const float sk0 = scalek[lr], sk1 = scalek[16 + lr];
        #pragma unroll
        for (int dti = 0; dti < 4; ++dti) {
            #pragma unroll
            for (int r = 0; r < 4; ++r) {
                int d = (wave * 4 + dti) * 16 + lg * 4 + r;
                ob[d * KC + lr]      = vv[dti][0][r] * sk0;
                ob[d * KC + 16 + lr] = vv[dti][1][r] * sk1;
            }
        }
    }
}

extern "C" void kernel_launch(void* const* d_in, const int* in_sizes, int n_in,
                              void* d_out, int out_size, void* d_ws, size_t ws_size,
                              hipStream_t stream) {
    const float* x        = (const float*)d_in[0];
    const float* clusters = (const float*)d_in[1];
    const float* bn_w     = (const float*)d_in[2];
    const float* bn_b     = (const float*)d_in[3];
    const float* bn_rm    = (const float*)d_in[4];
    const float* bn_rv    = (const float*)d_in[5];
    const float* c2       = (const float*)d_in[6];
    float* out = (float*)d_out;

    u16*   cTs  = (u16*)d_ws;
    float* tvec = (float*)((char*)d_ws + KT * DIM * sizeof(u16));

    const int B = in_sizes[0] / (NPT * DIM);

    prep_kernel<<<KT, 256, 0, stream>>>(clusters, bn_w, bn_b, bn_rm, bn_rv, cTs, tvec);
    vlad_kernel<<<B, 512, 0, stream>>>(x, c2, cTs, tvec, out);
}

// Round 5
// 406.203 us; speedup vs baseline: 1.2722x; 1.0788x over previous
//
#include <hip/hip_runtime.h>

typedef unsigned short u16;
typedef unsigned int u32;
typedef __attribute__((ext_vector_type(8))) short short8;
typedef __attribute__((ext_vector_type(4))) float f32x4;
typedef __attribute__((ext_vector_type(4))) u32 u32x4;
typedef __attribute__((ext_vector_type(2))) u32 u32x2;

#define NPT 128
#define DIM 512
#define KT 48
#define KC 32
#define BPB 16   // batches per block (persistent pipeline)

__device__ __forceinline__ u16 f2bf(float f) {
    unsigned u = __builtin_bit_cast(unsigned, f);
    return (u16)((u + 0x7FFFu + ((u >> 16) & 1u)) >> 16);
}

__device__ __forceinline__ u32 cvtpk(float lo, float hi) {
    u32 r;
    asm("v_cvt_pk_bf16_f32 %0, %1, %2" : "=v"(r) : "v"(lo), "v"(hi));
    return r;
}

// bank swizzle: 16B-granular XOR inside a 1KB row; distinct for rows n..n+7
// (phase-1 groups) AND for rows n, n+8, n+16, n+24 (phase-2 gather groups)
__device__ __forceinline__ int swz(int n) {
    return ((n & 7) ^ ((n >> 3) & 7)) << 4;
}

// Fold BN into clusters: cTs[k][d] = bf16(clusters[d][k] * s_k), t[k] = b_k - rm_k*s_k
__global__ void prep_kernel(const float* __restrict__ clusters,
                            const float* __restrict__ bn_w,
                            const float* __restrict__ bn_b,
                            const float* __restrict__ bn_rm,
                            const float* __restrict__ bn_rv,
                            u16* __restrict__ cTs,
                            float* __restrict__ tvec) {
    const int k = blockIdx.x;
    const float s = bn_w[k] * rsqrtf(bn_rv[k] + 1e-5f);
    if (threadIdx.x == 0) tvec[k] = bn_b[k] - bn_rm[k] * s;
    for (int d = threadIdx.x; d < DIM; d += blockDim.x)
        cTs[k * DIM + d] = f2bf(clusters[d * KT + k] * s);
}

__global__ __launch_bounds__(512)
void vlad_kernel(const float* __restrict__ x,
                 const float* __restrict__ c2,     // [512][32] fp32
                 const u16* __restrict__ cTs,      // [48][512] bf16
                 const float* __restrict__ tvec,   // [48]
                 float* __restrict__ out) {
    __shared__ __align__(16) u16 xs[NPT * DIM];    // 128 KB, swizzled row-major
    __shared__ __align__(16) u16 aT[KC][136];      // assignment^T
    __shared__ float asum_part[8][KC];
    __shared__ float colsq_part[8][KC];

    const int tid  = threadIdx.x;
    const int wave = tid >> 6;
    const int lane = tid & 63;
    const int lr   = lane & 15;
    const int lg   = lane >> 4;

    const int b0i = blockIdx.x * BPB;

    const float t0 = tvec[lr], t1 = tvec[16 + lr], t2 = tvec[32 + lr];

    // ---- prologue: stage batch b0i (wave-self: wave w rows [16w,16w+16)) ----
    {
        const float* gxw = x + (size_t)b0i * (NPT * DIM) + (wave * 16) * DIM;
        #pragma unroll
        for (int bt = 0; bt < 4; ++bt) {
            f32x4 tmp[8];
            #pragma unroll
            for (int i = 0; i < 8; ++i) {
                int it = bt * 8 + i;
                tmp[i] = *(const f32x4*)(gxw + (it >> 1) * DIM + (it & 1) * 256 + lane * 4);
            }
            #pragma unroll
            for (int i = 0; i < 8; ++i) {
                int it = bt * 8 + i;
                int r = wave * 16 + (it >> 1);
                u32x2 w2;
                w2[0] = cvtpk(tmp[i][0], tmp[i][1]);
                w2[1] = cvtpk(tmp[i][2], tmp[i][3]);
                int off = ((it & 1) * 512 + lane * 8) ^ swz(r);
                *(u32x2*)((char*)xs + r * 1024 + off) = w2;
            }
        }
    }

    for (int m = 0; m < BPB; ++m) {
        const int bm = b0i + m;

        // ---- phase 1: logits for own 16 rows (xs holds batch bm) ----
        f32x4 acc0 = {0.f,0.f,0.f,0.f}, acc1 = {0.f,0.f,0.f,0.f}, acc2 = {0.f,0.f,0.f,0.f};
        {
            const int nrow = wave * 16 + lr;
            const int rowbase = nrow * 1024;
            const int sw = swz(nrow);
            #pragma unroll 2
            for (int step = 0; step < 16; ++step) {
                const int d0 = step * 32 + lg * 8;
                short8 af = *(const short8*)((const char*)xs + (rowbase + ((2 * d0) ^ sw)));
                short8 bb0 = *(const short8*)(cTs + (0 * 16 + lr) * DIM + d0);
                short8 bb1 = *(const short8*)(cTs + (1 * 16 + lr) * DIM + d0);
                short8 bb2 = *(const short8*)(cTs + (2 * 16 + lr) * DIM + d0);
                acc0 = __builtin_amdgcn_mfma_f32_16x16x32_bf16(af, bb0, acc0, 0, 0, 0);
                acc1 = __builtin_amdgcn_mfma_f32_16x16x32_bf16(af, bb1, acc1, 0, 0, 0);
                acc2 = __builtin_amdgcn_mfma_f32_16x16x32_bf16(af, bb2, acc2, 0, 0, 0);
            }
        }
        // ---- softmax over 48, keep 32; aT bf16; per-wave asum partials ----
        {
            float a0[4], a1[4];
            #pragma unroll
            for (int r = 0; r < 4; ++r) {
                float l0 = acc0[r] + t0, l1 = acc1[r] + t1, l2 = acc2[r] + t2;
                float mx = fmaxf(fmaxf(l0, l1), l2);
                #pragma unroll
                for (int o = 1; o < 16; o <<= 1) mx = fmaxf(mx, __shfl_xor(mx, o));
                float e0 = __expf(l0 - mx), e1 = __expf(l1 - mx), e2 = __expf(l2 - mx);
                float s = e0 + e1 + e2;
                #pragma unroll
                for (int o = 1; o < 16; o <<= 1) s += __shfl_xor(s, o);
                float inv = 1.0f / s;
                a0[r] = e0 * inv; a1[r] = e1 * inv;
            }
            float p0 = 0.f, p1 = 0.f;
            #pragma unroll
            for (int r = 0; r < 4; ++r) {
                int n = wave * 16 + lg * 4 + r;
                aT[lr][n]      = f2bf(a0[r]);
                aT[16 + lr][n] = f2bf(a1[r]);
                p0 += a0[r]; p1 += a1[r];
            }
            p0 += __shfl_xor(p0, 16); p0 += __shfl_xor(p0, 32);
            p1 += __shfl_xor(p1, 16); p1 += __shfl_xor(p1, 32);
            if (lane < 16) { asum_part[wave][lane] = p0; asum_part[wave][16 + lane] = p1; }
        }
        __syncthreads();   // b1: aT + asum_part ready

        // ---- phase 2 (+ interleaved prefetch of batch m+1's own rows) ----
        const int pm = (m + 1 < BPB) ? bm + 1 : bm;   // clamp (last iter re-reads, harmless)
        const float* nx = x + (size_t)pm * (NPT * DIM) + (wave * 16) * DIM;
        u32x4 stg[16];
        f32x4 vacc[4][2];
        #pragma unroll
        for (int i = 0; i < 4; ++i) {
            vacc[i][0] = (f32x4){0.f,0.f,0.f,0.f};
            vacc[i][1] = (f32x4){0.f,0.f,0.f,0.f};
        }
        #pragma unroll
        for (int ns = 0; ns < 4; ++ns) {
            // issue prefetch loads for rows ns*4 .. ns*4+3 (issued before compute)
            f32x4 t[8];
            #pragma unroll
            for (int rr = 0; rr < 4; ++rr) {
                int i = ns * 4 + rr;
                t[2 * rr]     = *(const f32x4*)(nx + i * DIM + lane * 8);
                t[2 * rr + 1] = *(const f32x4*)(nx + i * DIM + lane * 8 + 4);
            }
            // compute this ns-step
            short8 bf0 = *(const short8*)(&aT[lr][ns * 32 + lg * 8]);
            short8 bf1 = *(const short8*)(&aT[16 + lr][ns * 32 + lg * 8]);
            const int n0 = ns * 32 + lg * 8;
            const int q  = (ns * 4 + lg) & 7;
            const char* pbase = (const char*)xs + n0 * 1024;
            #pragma unroll
            for (int dti = 0; dti < 4; ++dti) {
                const int d = (wave * 4 + dti) * 16 + lr;
                const int twod = 2 * d;
                short8 af;
                #pragma unroll
                for (int j = 0; j < 8; ++j)
                    af[j] = *(const short*)(pbase + j * 1024 + (twod ^ ((j ^ q) << 4)));
                vacc[dti][0] = __builtin_amdgcn_mfma_f32_16x16x32_bf16(af, bf0, vacc[dti][0], 0, 0, 0);
                vacc[dti][1] = __builtin_amdgcn_mfma_f32_16x16x32_bf16(af, bf1, vacc[dti][1], 0, 0, 0);
            }
            // convert landed prefetch to bf16 payload
            #pragma unroll
            for (int rr = 0; rr < 4; ++rr) {
                int i = ns * 4 + rr;
                u32x4 w;
                w[0] = cvtpk(t[2 * rr][0],     t[2 * rr][1]);
                w[1] = cvtpk(t[2 * rr][2],     t[2 * rr][3]);
                w[2] = cvtpk(t[2 * rr + 1][0], t[2 * rr + 1][1]);
                w[3] = cvtpk(t[2 * rr + 1][2], t[2 * rr + 1][3]);
                stg[i] = w;
            }
        }
        __syncthreads();   // e: all phase-2 xs/aT reads complete

        // ---- write prefetched batch into xs (own rows; wave-self ordering) ----
        #pragma unroll
        for (int i = 0; i < 16; ++i) {
            int r = wave * 16 + i;
            *(u32x4*)((char*)xs + r * 1024 + ((lane * 16) ^ swz(r))) = stg[i];
        }

        // ---- epilogue ----
        float as0 = 0.f, as1 = 0.f;
        #pragma unroll
        for (int w2 = 0; w2 < 8; ++w2) {
            as0 += asum_part[w2][lr];
            as1 += asum_part[w2][16 + lr];
        }
        float cs0 = 0.f, cs1 = 0.f;
        #pragma unroll
        for (int dti = 0; dti < 4; ++dti) {
            #pragma unroll
            for (int r = 0; r < 4; ++r) {
                int d = (wave * 4 + dti) * 16 + lg * 4 + r;
                float v0 = vacc[dti][0][r] - as0 * c2[d * KC + lr];
                float v1 = vacc[dti][1][r] - as1 * c2[d * KC + 16 + lr];
                vacc[dti][0][r] = v0; vacc[dti][1][r] = v1;
                cs0 += v0 * v0; cs1 += v1 * v1;
            }
        }
        cs0 += __shfl_xor(cs0, 16); cs0 += __shfl_xor(cs0, 32);
        cs1 += __shfl_xor(cs1, 16); cs1 += __shfl_xor(cs1, 32);
        if (lane < 16) { colsq_part[wave][lane] = cs0; colsq_part[wave][16 + lane] = cs1; }
        __syncthreads();   // colsq-b
        float sq0 = 0.f, sq1 = 0.f;
        #pragma unroll
        for (int w2 = 0; w2 < 8; ++w2) {
            sq0 += colsq_part[w2][lr];
            sq1 += colsq_part[w2][16 + lr];
        }
        float cn0 = sqrtf(sq0), cn1 = sqrtf(sq1);
        float s10 = 1.0f / fmaxf(cn0, 1e-12f);
        float s11 = 1.0f / fmaxf(cn1, 1e-12f);
        float c10 = cn0 * s10, c11 = cn1 * s11;
        float tot = c10 * c10 + c11 * c11;
        #pragma unroll
        for (int o = 1; o < 16; o <<= 1) tot += __shfl_xor(tot, o);
        float gs = 1.0f / fmaxf(sqrtf(tot), 1e-12f);
        float sk0 = s10 * gs, sk1 = s11 * gs;
        {
            float* ob = out + (size_t)bm * (DIM * KC);
            #pragma unroll
            for (int dti = 0; dti < 4; ++dti) {
                #pragma unroll
                for (int r = 0; r < 4; ++r) {
                    int d = (wave * 4 + dti) * 16 + lg * 4 + r;
                    ob[d * KC + lr]      = vacc[dti][0][r] * sk0;
                    ob[d * KC + 16 + lr] = vacc[dti][1][r] * sk1;
                }
            }
        }
        // no barrier needed: next phase-1 reads only own xs rows (same-wave order);
        // cross-wave LDS writes in next iter are all behind b1(m+1)/colsq-b(m).
    }
}

extern "C" void kernel_launch(void* const* d_in, const int* in_sizes, int n_in,
                              void* d_out, int out_size, void* d_ws, size_t ws_size,
                              hipStream_t stream) {
    const float* x        = (const float*)d_in[0];
    const float* clusters = (const float*)d_in[1];
    const float* bn_w     = (const float*)d_in[2];
    const float* bn_b     = (const float*)d_in[3];
    const float* bn_rm    = (const float*)d_in[4];
    const float* bn_rv    = (const float*)d_in[5];
    const float* c2       = (const float*)d_in[6];
    float* out = (float*)d_out;

    u16*   cTs  = (u16*)d_ws;
    float* tvec = (float*)((char*)d_ws + KT * DIM * sizeof(u16));

    const int B = in_sizes[0] / (NPT * DIM);

    prep_kernel<<<KT, 256, 0, stream>>>(clusters, bn_w, bn_b, bn_rm, bn_rv, cTs, tvec);
    vlad_kernel<<<B / BPB, 512, 0, stream>>>(x, c2, cTs, tvec, out);
}